// Round 15
// baseline (255.577 us; speedup 1.0000x reference)
//
#include <hip/hip_runtime.h>

#define K_C    500
#define KPAD   512
#define DIM    768
#define NROWS  65536
#define BM     64
#define NCH    (DIM / 8)       // 96 8-float chunks
#define THREADS 1024
#define TAU    1.0f

// ---- d_ws layout (bytes) ----
#define WS_CSQ  64
#define WS_LIST 4096
#define WS_CHI  270336

typedef __attribute__((ext_vector_type(8)))  short bf16x8;
typedef __attribute__((ext_vector_type(16))) float f32x16;

__device__ __forceinline__ ushort f2bf(float f) {
    unsigned x = __float_as_uint(f);
    unsigned r = (x + 0x7fffu + ((x >> 16) & 1u)) >> 16;   // RNE
    return (ushort)r;
}

// ---------------------------------------------------------------------------
// Pre-kernel 1: centers fp32 -> bf16 (RNE), chunk-major tile layout:
// unit u = g*512 + r (global chunk g 0..95, center r 0..511) holds
// c[r][g*8 .. +7]. Zero-pads rows 500..511; zeroes the rescue counter.
// ---------------------------------------------------------------------------
__global__ void convert_kernel(const float* __restrict__ c, ushort* __restrict__ chi,
                               int* __restrict__ count) {
    int gid = blockIdx.x * 256 + threadIdx.x;
    if (gid == 0) *count = 0;
    int g = gid >> 9;
    int r = gid & 511;
    int kbase = g * 8;

    ushort h[8];
    if (r < K_C) {
        #pragma unroll
        for (int e = 0; e < 8; ++e) h[e] = f2bf(c[(size_t)r * DIM + kbase + e]);
    } else {
        #pragma unroll
        for (int e = 0; e < 8; ++e) h[e] = 0;
    }
    ushort* ph = chi + (size_t)gid * 8;
    #pragma unroll
    for (int e = 0; e < 8; ++e) ph[e] = h[e];
}

// ---------------------------------------------------------------------------
// Pre-kernel 2: csq[k] = ||c_k||^2 fp32; pads 500..511 with +INF.
// ---------------------------------------------------------------------------
__global__ void csq_kernel(const float* __restrict__ c, float* __restrict__ csq) {
    int wid  = (blockIdx.x * blockDim.x + threadIdx.x) >> 6;
    int lane = threadIdx.x & 63;
    if (wid >= KPAD) return;
    if (wid >= K_C) { if (lane == 0) csq[wid] = INFINITY; return; }
    const float* row = c + (size_t)wid * DIM;
    float s = 0.f;
    #pragma unroll
    for (int j = 0; j < DIM / 64; ++j) {
        float v = row[lane + j * 64];
        s += v * v;
    }
    #pragma unroll
    for (int m = 32; m; m >>= 1) s += __shfl_xor(s, m, 64);
    if (lane == 0) csq[wid] = s;
}

// ---------------------------------------------------------------------------
// Main kernel (round 15): BARRIER-FREE K-LOOP.
// Diagnosis r6-r14: per-iteration __syncthreads exposes full L2->LDS stage
// latency in lockstep (time pinned at 145-220us across all structures);
// r12's barrier-free attempt failed on its A-gather (64 lines/instr), not
// the structure. Here: A (64 rows, full K) is staged ONCE into 98 KB LDS
// via coalesced flat float4 loads + ONE barrier; the k-loop then has no
// barriers, no LDS writes, no gather. B streams global->reg from the
// chunk-major ws tiles (512B contiguous per half-wave). 16 waves = 2wm x 8wn,
// Mf=1 x Nf=2 -> acc 32 regs, launch_bounds(1024,4) -> 4 waves/SIMD,
// every wave self-paced; compiler pipelines loads across iterations.
// ---------------------------------------------------------------------------
__global__ __launch_bounds__(THREADS, 4) void kmeans_mfma(
        const float* __restrict__ x, const char* __restrict__ ws,
        int* __restrict__ out) {
    __shared__ __align__(16) ushort Ah[NCH][BM][8];      // 96 KB
    __shared__ float rv1[8][BM];                         // 2 KB
    __shared__ float rv2[8][BM];                         // 2 KB
    __shared__ int   ridx[8][BM];                        // 2 KB

    const int tid  = threadIdx.x;
    const int w    = tid >> 6;          // wave 0..15
    const int lane = tid & 63;
    const int l31  = lane & 31;
    const int lh   = lane >> 5;
    const int wm   = w >> 3;            // 0..1 row half (32 rows each)
    const int wn   = w & 7;             // 0..7 col octant (64 cols each)
    const int rowBase = blockIdx.x * BM;

    const ushort* __restrict__ Bws = (const ushort*)(ws + WS_CHI);
    const float* csq  = (const float*)(ws + WS_CSQ);
    int* count = (int*)ws;
    int* list  = (int*)(ws + WS_LIST);

    // ---- stage A once: 64 rows x 768 dims, coalesced flat float4 loads ----
    {
        const float* xg = x + (size_t)rowBase * DIM;
        #pragma unroll
        for (int i = 0; i < 12; ++i) {
            int f   = i * 1024 + tid;          // flat float4 index, 0..12287
            int row = f / 192;                 // 192 float4 per row
            int c4  = f - row * 192;
            float4 v = *reinterpret_cast<const float4*>(xg + (size_t)f * 4);
            ushort4 u = make_ushort4(f2bf(v.x), f2bf(v.y), f2bf(v.z), f2bf(v.w));
            *reinterpret_cast<ushort4*>(&Ah[c4 >> 1][row][(c4 & 1) * 4]) = u;
        }
    }
    __syncthreads();   // the ONLY block-wide sync before the epilogue

    // ---- barrier-free K-loop: 48 chunk-pairs, 2 MFMA each ----
    // B unit for (g2, lh, nf): chunk g = g2*2 + lh; offset
    // (g*512 + wn*64 + nf*32 + l31) * 8 ushorts.
    const ushort* __restrict__ pB = Bws + ((size_t)lh * 512 + wn * 64 + l31) * 8;
    f32x16 acc[2] = {};

    #pragma unroll 4
    for (int g2 = 0; g2 < 48; ++g2) {
        const int j = g2 * 2 + lh;
        bf16x8 ah = *reinterpret_cast<const bf16x8*>(&Ah[j][wm * 32 + l31][0]);
        const ushort* b = pB + (size_t)g2 * 8192;    // g2*2*512*8
        bf16x8 b0 = *reinterpret_cast<const bf16x8*>(b);
        bf16x8 b1 = *reinterpret_cast<const bf16x8*>(b + 256);  // nf=1: +32*8
        acc[0] = __builtin_amdgcn_mfma_f32_32x32x16_bf16(ah, b0, acc[0], 0, 0, 0);
        acc[1] = __builtin_amdgcn_mfma_f32_32x32x16_bf16(ah, b1, acc[1], 0, 0, 0);
    }

    // ---- epilogue: per-row (best, second, idx) over this wave's 64 cols ----
    float cq[2];
    #pragma unroll
    for (int nf = 0; nf < 2; ++nf) cq[nf] = csq[wn * 64 + nf * 32 + l31];

    #pragma unroll
    for (int reg = 0; reg < 16; ++reg) {
        float v0 = fmaf(-2.f, acc[0][reg], cq[0]);
        float v1 = fmaf(-2.f, acc[1][reg], cq[1]);
        int  c0 = wn * 64 + l31;
        int  c1 = c0 + 32;
        float b1, b2; int i1;
        if (v1 < v0) { b1 = v1; i1 = c1; b2 = v0; }
        else         { b1 = v0; i1 = c0; b2 = v1; }
        #pragma unroll
        for (int m = 1; m < 32; m <<= 1) {
            float o1 = __shfl_xor(b1, m, 64);
            float o2 = __shfl_xor(b2, m, 64);
            int   oi = __shfl_xor(i1, m, 64);
            b2 = fminf(fminf(b2, o2), fmaxf(b1, o1));
            if (o1 < b1 || (o1 == b1 && oi < i1)) { b1 = o1; i1 = oi; }
        }
        int row = wm * 32 + (reg & 3) + 8 * (reg >> 2) + 4 * lh;
        if (l31 == 0) { rv1[wn][row] = b1; rv2[wn][row] = b2; ridx[wn][row] = i1; }
    }
    __syncthreads();

    // ---- merge 8 col-octants per row, write out, flag tight margins ----
    if (tid < BM) {
        float b1 = INFINITY, b2 = INFINITY; int i1 = 0;
        #pragma unroll
        for (int ww = 0; ww < 8; ++ww) {
            float a1 = rv1[ww][tid], a2 = rv2[ww][tid];
            int   ai = ridx[ww][tid];
            b2 = fminf(fminf(b2, a2), fmaxf(b1, a1));
            if (a1 < b1 || (a1 == b1 && ai < i1)) { b1 = a1; i1 = ai; }
        }
        out[rowBase + tid] = i1;
        if (b2 - b1 < TAU) {
            int p = atomicAdd(count, 1);
            list[p] = rowBase + tid;
        }
    }
}

// ---------------------------------------------------------------------------
// Rescue v4 (unchanged): exact fp32, register-tiled. 512 threads =
// 2 row-groups x 256 center-pairs; per thread 8 rows x 2 centers.
// ---------------------------------------------------------------------------
__global__ __launch_bounds__(512) void rescue_kernel(
        const float* __restrict__ x, const float* __restrict__ c,
        const char* __restrict__ ws, int* __restrict__ out) {
    __shared__ __align__(16) float xs[16][DIM];   // 48 KB
    __shared__ float mv[16][4];
    __shared__ int   mi[16][4];
    __shared__ int   rows_s[16];
    const float* csq = (const float*)(ws + WS_CSQ);
    const int* list  = (const int*)(ws + WS_LIST);
    const int n = *(const int*)ws;
    const int tid  = threadIdx.x;
    const int wv   = tid >> 6;          // wave 0..7
    const int rg   = tid >> 8;          // row group 0..1 (rows rg*8..+7)
    const int cg   = tid & 255;         // center pair id
    const int k0 = cg;                  // centers k0, k0+256 (asc for ties)
    const int k1 = cg + 256;
    const float* c0 = c + (size_t)min(k0, K_C - 1) * DIM;
    const float* c1 = c + (size_t)min(k1, K_C - 1) * DIM;
    const float cq0 = csq[k0];
    const float cq1 = csq[k1];

    for (int g = blockIdx.x; g * 16 < n; g += gridDim.x) {
        const int base = g * 16;
        const int cnt  = min(16, n - base);
        if (tid < 16) rows_s[tid] = list[base + min(tid, cnt - 1)];
        __syncthreads();
        for (int idx = tid; idx < 16 * (DIM / 4); idx += 512) {
            int r = idx / (DIM / 4), dc = idx - r * (DIM / 4);
            *reinterpret_cast<float4*>(&xs[r][dc * 4]) =
                *reinterpret_cast<const float4*>(&x[(size_t)rows_s[r] * DIM + dc * 4]);
        }
        __syncthreads();

        float d0[8], d1[8];
        #pragma unroll
        for (int i = 0; i < 8; ++i) { d0[i] = 0.f; d1[i] = 0.f; }

        #pragma unroll 2
        for (int dq = 0; dq < DIM / 4; ++dq) {
            float4 cv0 = *reinterpret_cast<const float4*>(&c0[dq * 4]);
            float4 cv1 = *reinterpret_cast<const float4*>(&c1[dq * 4]);
            #pragma unroll
            for (int i = 0; i < 8; ++i) {
                float4 xv = *reinterpret_cast<const float4*>(&xs[rg * 8 + i][dq * 4]);
                d0[i] = fmaf(xv.x, cv0.x, d0[i]);
                d0[i] = fmaf(xv.y, cv0.y, d0[i]);
                d0[i] = fmaf(xv.z, cv0.z, d0[i]);
                d0[i] = fmaf(xv.w, cv0.w, d0[i]);
                d1[i] = fmaf(xv.x, cv1.x, d1[i]);
                d1[i] = fmaf(xv.y, cv1.y, d1[i]);
                d1[i] = fmaf(xv.z, cv1.z, d1[i]);
                d1[i] = fmaf(xv.w, cv1.w, d1[i]);
            }
        }

        float bv[8]; int bi[8];
        #pragma unroll
        for (int i = 0; i < 8; ++i) {
            float v0 = fmaf(-2.f, d0[i], cq0);
            float v1 = fmaf(-2.f, d1[i], cq1);
            if (v1 < v0) { bv[i] = v1; bi[i] = k1; }
            else         { bv[i] = v0; bi[i] = k0; }   // k0 < k1: ties keep k0
        }
        #pragma unroll
        for (int m = 1; m < 64; m <<= 1) {
            #pragma unroll
            for (int i = 0; i < 8; ++i) {
                float ov = __shfl_xor(bv[i], m, 64);
                int   oi = __shfl_xor(bi[i], m, 64);
                if (ov < bv[i] || (ov == bv[i] && oi < bi[i])) { bv[i] = ov; bi[i] = oi; }
            }
        }
        if ((tid & 63) == 0) {
            #pragma unroll
            for (int i = 0; i < 8; ++i) { mv[rg * 8 + i][wv & 3] = bv[i]; mi[rg * 8 + i][wv & 3] = bi[i]; }
        }
        __syncthreads();
        if (tid < cnt) {
            float b = mv[tid][0]; int i = mi[tid][0];
            #pragma unroll
            for (int q = 1; q < 4; ++q) {
                if (mv[tid][q] < b || (mv[tid][q] == b && mi[tid][q] < i)) {
                    b = mv[tid][q]; i = mi[tid][q];
                }
            }
            out[rows_s[tid]] = i;
        }
        __syncthreads();
    }
}

extern "C" void kernel_launch(void* const* d_in, const int* in_sizes, int n_in,
                              void* d_out, int out_size, void* d_ws, size_t ws_size,
                              hipStream_t stream) {
    const float* x = (const float*)d_in[0];
    const float* c = (const float*)d_in[1];
    char* ws = (char*)d_ws;
    int* out = (int*)d_out;

    convert_kernel<<<dim3(192), dim3(256), 0, stream>>>(
        c, (ushort*)(ws + WS_CHI), (int*)ws);
    csq_kernel<<<dim3(128), dim3(256), 0, stream>>>(c, (float*)(ws + WS_CSQ));
    kmeans_mfma<<<dim3(NROWS / BM), dim3(THREADS), 0, stream>>>(x, ws, out);
    rescue_kernel<<<dim3(256), dim3(512), 0, stream>>>(x, c, ws, out);
}

// Round 16
// 212.255 us; speedup vs baseline: 1.2041x; 1.2041x over previous
//
#include <hip/hip_runtime.h>

#define K_C    500
#define KPAD   512
#define DIM    768
#define NROWS  65536
#define BM     64
#define BK     64
#define NKT    (DIM / BK)      // 12 K-tiles
#define THREADS 512
#define TAU    1.0f

// ---- d_ws layout (bytes) ----
#define WS_CSQ  64
#define WS_LIST 4096
#define WS_CHI  270336

typedef __attribute__((ext_vector_type(8)))  short bf16x8;
typedef __attribute__((ext_vector_type(16))) float f32x16;

__device__ __forceinline__ ushort f2bf(float f) {
    unsigned x = __float_as_uint(f);
    unsigned r = (x + 0x7fffu + ((x >> 16) & 1u)) >> 16;   // RNE
    return (ushort)r;
}

#define GLOAD16(g, l)                                                        \
    __builtin_amdgcn_global_load_lds(                                        \
        (__attribute__((address_space(1))) void*)(g),                        \
        (__attribute__((address_space(3))) void*)(l), 16, 0, 0)

// ---------------------------------------------------------------------------
// Pre-kernel 1: centers fp32 -> bf16 (RNE), GLOBAL chunk-major layout:
// unit u = g*512 + r (chunk g 0..95, center r 0..511) holds c[r][g*8..+7].
// Zero-pads rows 500..511; zeroes the rescue counter.
// ---------------------------------------------------------------------------
__global__ void convert_kernel(const float* __restrict__ c, ushort* __restrict__ chi,
                               int* __restrict__ count) {
    int gid = blockIdx.x * 256 + threadIdx.x;
    if (gid == 0) *count = 0;
    int g = gid >> 9;
    int r = gid & 511;
    int kbase = g * 8;

    ushort h[8];
    if (r < K_C) {
        #pragma unroll
        for (int e = 0; e < 8; ++e) h[e] = f2bf(c[(size_t)r * DIM + kbase + e]);
    } else {
        #pragma unroll
        for (int e = 0; e < 8; ++e) h[e] = 0;
    }
    ushort* ph = chi + (size_t)gid * 8;
    #pragma unroll
    for (int e = 0; e < 8; ++e) ph[e] = h[e];
}

// ---------------------------------------------------------------------------
// Pre-kernel 2: csq[k] = ||c_k||^2 fp32; pads 500..511 with +INF.
// ---------------------------------------------------------------------------
__global__ void csq_kernel(const float* __restrict__ c, float* __restrict__ csq) {
    int wid  = (blockIdx.x * blockDim.x + threadIdx.x) >> 6;
    int lane = threadIdx.x & 63;
    if (wid >= KPAD) return;
    if (wid >= K_C) { if (lane == 0) csq[wid] = INFINITY; return; }
    const float* row = c + (size_t)wid * DIM;
    float s = 0.f;
    #pragma unroll
    for (int j = 0; j < DIM / 64; ++j) {
        float v = row[lane + j * 64];
        s += v * v;
    }
    #pragma unroll
    for (int m = 32; m; m >>= 1) s += __shfl_xor(s, m, 64);
    if (lane == 0) csq[wid] = s;
}

// ---------------------------------------------------------------------------
// Main kernel (round 16): r13's proven config (BM=64, 512 thr, acc 64,
// 4 waves/SIMD, 2 blocks/CU) with BK=64 -> HALF the barrier slots (12 vs 24).
// Discriminating experiment: r6-r15 pin the kernel at 145-220us across all
// structures; r13 (24 slots, 2 blocks/CU) = 147us best. If per-slot cost is
// exposed-latency (drain at barrier b), 12 slots -> ~100us; if stage-BW,
// wash. B tile 64 KB single-buffer (8 GLOAD16/wave, global-chunk-major ws);
// A tile 8 KB staged by ALL 512 threads (8 floats each, slot = row^(j<<1));
// compute 4 k-steps x 4 nf = 16 MFMA/wave/slot. LDS 76.8 KB -> 2 blocks/CU.
// ---------------------------------------------------------------------------
__global__ __launch_bounds__(THREADS, 4) void kmeans_mfma(
        const float* __restrict__ x, const char* __restrict__ ws,
        int* __restrict__ out) {
    __shared__ __align__(16) ushort Bh[8][KPAD][8];      // 64 KB
    __shared__ __align__(16) ushort Ah[8][BM][8];        // 8 KB
    __shared__ float rv1[4][BM];                         // 1 KB
    __shared__ float rv2[4][BM];                         // 1 KB
    __shared__ int   ridx[4][BM];                        // 1 KB

    const int tid  = threadIdx.x;
    const int w    = tid >> 6;          // wave 0..7
    const int lane = tid & 63;
    const int l31  = lane & 31;
    const int lh   = lane >> 5;
    const int wm   = w >> 2;            // 0..1 row half (32 rows each)
    const int wn   = w & 3;             // 0..3 col quarter (128 cols each)
    const int rowBase = blockIdx.x * BM;

    // A staging (ALL 512 threads): thread t -> row t>>3 (0..63), chunk j = t&7
    const int srow = tid >> 3;
    const int sj   = tid & 7;
    const int sslot = srow ^ (sj << 1);   // bank-spread write slot
    const float* xsrc = x + (size_t)(rowBase + srow) * DIM + sj * 8;

    const char* wsChi = ws + WS_CHI;
    const float* csq  = (const float*)(ws + WS_CSQ);
    int* count = (int*)ws;
    int* list  = (int*)(ws + WS_LIST);

    f32x16 acc[4] = {};

    // ---- preload + convert A tile 0 ----
    uint4 hv;
    {
        float4 xa = *reinterpret_cast<const float4*>(xsrc);
        float4 xb = *reinterpret_cast<const float4*>(xsrc + 4);
        float v[8] = {xa.x, xa.y, xa.z, xa.w, xb.x, xb.y, xb.z, xb.w};
        uint h[8];
        #pragma unroll
        for (int e = 0; e < 8; ++e) h[e] = f2bf(v[e]);
        hv = make_uint4(h[0] | (h[1] << 16), h[2] | (h[3] << 16),
                        h[4] | (h[5] << 16), h[6] | (h[7] << 16));
    }

    for (int kt = 0; kt < NKT; ++kt) {
        __syncthreads();   // (a) prev compute done; Bh/Ah safe to overwrite

        // ---- stage B(kt): 8 waves x 8 KB = 64 KB via global_load_lds ----
        {
            const char* sH = wsChi + (size_t)kt * 65536 + w * 8192 + lane * 16;
            char* dH = ((char*)Bh) + w * 8192;
            #pragma unroll
            for (int i = 0; i < 8; ++i) GLOAD16(sH + i * 1024, dH + i * 1024);
        }
        // ---- A write (pre-converted regs -> LDS, swizzled slot) ----
        *reinterpret_cast<uint4*>(&Ah[sj][sslot][0]) = hv;

        __syncthreads();   // (b) compiler drains vmcnt+lgkm: staged data visible

        // ---- prefetch next A floats (hidden under compute) ----
        float4 xa, xb;
        if (kt + 1 < NKT) {
            xa = *reinterpret_cast<const float4*>(xsrc + (kt + 1) * BK);
            xb = *reinterpret_cast<const float4*>(xsrc + (kt + 1) * BK + 4);
        }

        // ---- compute: 4 k-steps of 16, 4 MFMAs each ----
        __builtin_amdgcn_s_setprio(1);
        #pragma unroll
        for (int ks = 0; ks < 4; ++ks) {
            const int j = ks * 2 + lh;                     // chunk 0..7
            const int rsl = (wm * 32 + l31) ^ (j << 1);    // read slot (swizzle inverse)
            bf16x8 ah0 = *(const bf16x8*)&Ah[j][rsl][0];

            const ushort* pBh = &Bh[j][wn * 128 + l31][0];
            #pragma unroll
            for (int nf = 0; nf < 4; ++nf) {
                bf16x8 bh = *(const bf16x8*)(pBh + nf * 32 * 8);
                acc[nf] = __builtin_amdgcn_mfma_f32_32x32x16_bf16(ah0, bh, acc[nf], 0, 0, 0);
            }
        }
        __builtin_amdgcn_s_setprio(0);

        // ---- convert next A tile ----
        if (kt + 1 < NKT) {
            float v[8] = {xa.x, xa.y, xa.z, xa.w, xb.x, xb.y, xb.z, xb.w};
            uint h[8];
            #pragma unroll
            for (int e = 0; e < 8; ++e) h[e] = f2bf(v[e]);
            hv = make_uint4(h[0] | (h[1] << 16), h[2] | (h[3] << 16),
                            h[4] | (h[5] << 16), h[6] | (h[7] << 16));
        }
    }

    // ---- epilogue: per-row (best, second, idx) over this wave's 128 cols ----
    float cq[4];
    #pragma unroll
    for (int nf = 0; nf < 4; ++nf) cq[nf] = csq[wn * 128 + nf * 32 + l31];

    #pragma unroll
    for (int reg = 0; reg < 16; ++reg) {
        float v[4]; int col[4];
        #pragma unroll
        for (int nf = 0; nf < 4; ++nf) {
            v[nf]   = fmaf(-2.f, acc[nf][reg], cq[nf]);
            col[nf] = wn * 128 + nf * 32 + l31;
        }
        float paL, paH; int paI;
        if (v[1] < v[0]) { paL = v[1]; paI = col[1]; paH = v[0]; }
        else             { paL = v[0]; paI = col[0]; paH = v[1]; }
        float pbL, pbH; int pbI;
        if (v[3] < v[2]) { pbL = v[3]; pbI = col[3]; pbH = v[2]; }
        else             { pbL = v[2]; pbI = col[2]; pbH = v[3]; }
        float b1, b2; int i1;
        if (pbL < paL) { b1 = pbL; i1 = pbI; b2 = fminf(paL, pbH); }
        else           { b1 = paL; i1 = paI; b2 = fminf(pbL, paH); }
        #pragma unroll
        for (int m = 1; m < 32; m <<= 1) {
            float o1 = __shfl_xor(b1, m, 64);
            float o2 = __shfl_xor(b2, m, 64);
            int   oi = __shfl_xor(i1, m, 64);
            b2 = fminf(fminf(b2, o2), fmaxf(b1, o1));
            if (o1 < b1 || (o1 == b1 && oi < i1)) { b1 = o1; i1 = oi; }
        }
        int row = wm * 32 + (reg & 3) + 8 * (reg >> 2) + 4 * lh;
        if (l31 == 0) { rv1[wn][row] = b1; rv2[wn][row] = b2; ridx[wn][row] = i1; }
    }
    __syncthreads();

    // ---- merge 4 col-quarters per row, write out, flag tight margins ----
    if (tid < BM) {
        float b1 = INFINITY, b2 = INFINITY; int i1 = 0;
        #pragma unroll
        for (int ww = 0; ww < 4; ++ww) {
            float a1 = rv1[ww][tid], a2 = rv2[ww][tid];
            int   ai = ridx[ww][tid];
            b2 = fminf(fminf(b2, a2), fmaxf(b1, a1));
            if (a1 < b1 || (a1 == b1 && ai < i1)) { b1 = a1; i1 = ai; }
        }
        out[rowBase + tid] = i1;
        if (b2 - b1 < TAU) {
            int p = atomicAdd(count, 1);
            list[p] = rowBase + tid;
        }
    }
}

// ---------------------------------------------------------------------------
// Rescue v4 (unchanged): exact fp32, register-tiled. 512 threads =
// 2 row-groups x 256 center-pairs; per thread 8 rows x 2 centers.
// ---------------------------------------------------------------------------
__global__ __launch_bounds__(512) void rescue_kernel(
        const float* __restrict__ x, const float* __restrict__ c,
        const char* __restrict__ ws, int* __restrict__ out) {
    __shared__ __align__(16) float xs[16][DIM];   // 48 KB
    __shared__ float mv[16][4];
    __shared__ int   mi[16][4];
    __shared__ int   rows_s[16];
    const float* csq = (const float*)(ws + WS_CSQ);
    const int* list  = (const int*)(ws + WS_LIST);
    const int n = *(const int*)ws;
    const int tid  = threadIdx.x;
    const int wv   = tid >> 6;          // wave 0..7
    const int rg   = tid >> 8;          // row group 0..1 (rows rg*8..+7)
    const int cg   = tid & 255;         // center pair id
    const int k0 = cg;                  // centers k0, k0+256 (asc for ties)
    const int k1 = cg + 256;
    const float* c0 = c + (size_t)min(k0, K_C - 1) * DIM;
    const float* c1 = c + (size_t)min(k1, K_C - 1) * DIM;
    const float cq0 = csq[k0];
    const float cq1 = csq[k1];

    for (int g = blockIdx.x; g * 16 < n; g += gridDim.x) {
        const int base = g * 16;
        const int cnt  = min(16, n - base);
        if (tid < 16) rows_s[tid] = list[base + min(tid, cnt - 1)];
        __syncthreads();
        for (int idx = tid; idx < 16 * (DIM / 4); idx += 512) {
            int r = idx / (DIM / 4), dc = idx - r * (DIM / 4);
            *reinterpret_cast<float4*>(&xs[r][dc * 4]) =
                *reinterpret_cast<const float4*>(&x[(size_t)rows_s[r] * DIM + dc * 4]);
        }
        __syncthreads();

        float d0[8], d1[8];
        #pragma unroll
        for (int i = 0; i < 8; ++i) { d0[i] = 0.f; d1[i] = 0.f; }

        #pragma unroll 2
        for (int dq = 0; dq < DIM / 4; ++dq) {
            float4 cv0 = *reinterpret_cast<const float4*>(&c0[dq * 4]);
            float4 cv1 = *reinterpret_cast<const float4*>(&c1[dq * 4]);
            #pragma unroll
            for (int i = 0; i < 8; ++i) {
                float4 xv = *reinterpret_cast<const float4*>(&xs[rg * 8 + i][dq * 4]);
                d0[i] = fmaf(xv.x, cv0.x, d0[i]);
                d0[i] = fmaf(xv.y, cv0.y, d0[i]);
                d0[i] = fmaf(xv.z, cv0.z, d0[i]);
                d0[i] = fmaf(xv.w, cv0.w, d0[i]);
                d1[i] = fmaf(xv.x, cv1.x, d1[i]);
                d1[i] = fmaf(xv.y, cv1.y, d1[i]);
                d1[i] = fmaf(xv.z, cv1.z, d1[i]);
                d1[i] = fmaf(xv.w, cv1.w, d1[i]);
            }
        }

        float bv[8]; int bi[8];
        #pragma unroll
        for (int i = 0; i < 8; ++i) {
            float v0 = fmaf(-2.f, d0[i], cq0);
            float v1 = fmaf(-2.f, d1[i], cq1);
            if (v1 < v0) { bv[i] = v1; bi[i] = k1; }
            else         { bv[i] = v0; bi[i] = k0; }   // k0 < k1: ties keep k0
        }
        #pragma unroll
        for (int m = 1; m < 64; m <<= 1) {
            #pragma unroll
            for (int i = 0; i < 8; ++i) {
                float ov = __shfl_xor(bv[i], m, 64);
                int   oi = __shfl_xor(bi[i], m, 64);
                if (ov < bv[i] || (ov == bv[i] && oi < bi[i])) { bv[i] = ov; bi[i] = oi; }
            }
        }
        if ((tid & 63) == 0) {
            #pragma unroll
            for (int i = 0; i < 8; ++i) { mv[rg * 8 + i][wv & 3] = bv[i]; mi[rg * 8 + i][wv & 3] = bi[i]; }
        }
        __syncthreads();
        if (tid < cnt) {
            float b = mv[tid][0]; int i = mi[tid][0];
            #pragma unroll
            for (int q = 1; q < 4; ++q) {
                if (mv[tid][q] < b || (mv[tid][q] == b && mi[tid][q] < i)) {
                    b = mv[tid][q]; i = mi[tid][q];
                }
            }
            out[rows_s[tid]] = i;
        }
        __syncthreads();
    }
}

extern "C" void kernel_launch(void* const* d_in, const int* in_sizes, int n_in,
                              void* d_out, int out_size, void* d_ws, size_t ws_size,
                              hipStream_t stream) {
    const float* x = (const float*)d_in[0];
    const float* c = (const float*)d_in[1];
    char* ws = (char*)d_ws;
    int* out = (int*)d_out;

    convert_kernel<<<dim3(192), dim3(256), 0, stream>>>(
        c, (ushort*)(ws + WS_CHI), (int*)ws);
    csq_kernel<<<dim3(128), dim3(256), 0, stream>>>(c, (float*)(ws + WS_CSQ));
    kmeans_mfma<<<dim3(NROWS / BM), dim3(THREADS), 0, stream>>>(x, ws, out);
    rescue_kernel<<<dim3(256), dim3(512), 0, stream>>>(x, c, ws, out);
}

// Round 17
// 166.292 us; speedup vs baseline: 1.5369x; 1.2764x over previous
//
#include <hip/hip_runtime.h>

#define K_C    500
#define KPAD   512
#define DIM    768
#define NROWS  65536
#define BM     64
#define BK     64
#define NKT    (DIM / BK)      // 12 K-tiles
#define THREADS 512
#define TAU    1.0f

// ---- d_ws layout (bytes) ----
#define WS_CSQ  64
#define WS_LIST 4096
#define WS_CHI  270336
#define WS_CT   (270336 + 786432)          // 1056768: fp32 transposed centers
#define WS_NEED (WS_CT + 192 * 512 * 16)   // 2629632 bytes total

typedef __attribute__((ext_vector_type(8)))  short bf16x8;
typedef __attribute__((ext_vector_type(16))) float f32x16;

__device__ __forceinline__ ushort f2bf(float f) {
    unsigned x = __float_as_uint(f);
    unsigned r = (x + 0x7fffu + ((x >> 16) & 1u)) >> 16;   // RNE
    return (ushort)r;
}

#define GLOAD16(g, l)                                                        \
    __builtin_amdgcn_global_load_lds(                                        \
        (__attribute__((address_space(1))) void*)(g),                        \
        (__attribute__((address_space(3))) void*)(l), 16, 0, 0)

// ---------------------------------------------------------------------------
// Pre-kernel 1: centers fp32 -> bf16 (RNE), GLOBAL chunk-major layout:
// unit u = g*512 + r (chunk g 0..95, center r 0..511) holds c[r][g*8..+7].
// ALSO (if do_ct): writes fp32 transposed quads ct4[dq*512 + r] =
// c[r][dq*4..+3] (dq = g*2, g*2+1) for the coalesced rescue path.
// Zero-pads rows 500..511; zeroes the rescue counter.
// ---------------------------------------------------------------------------
__global__ void convert_kernel(const float* __restrict__ c, ushort* __restrict__ chi,
                               float4* __restrict__ ct4, int do_ct,
                               int* __restrict__ count) {
    int gid = blockIdx.x * 256 + threadIdx.x;
    if (gid == 0) *count = 0;
    int g = gid >> 9;
    int r = gid & 511;
    int kbase = g * 8;

    float v[8];
    if (r < K_C) {
        #pragma unroll
        for (int e = 0; e < 8; ++e) v[e] = c[(size_t)r * DIM + kbase + e];
    } else {
        #pragma unroll
        for (int e = 0; e < 8; ++e) v[e] = 0.f;
    }
    ushort* ph = chi + (size_t)gid * 8;
    #pragma unroll
    for (int e = 0; e < 8; ++e) ph[e] = f2bf(v[e]);

    if (do_ct) {
        ct4[(size_t)(g * 2 + 0) * 512 + r] = make_float4(v[0], v[1], v[2], v[3]);
        ct4[(size_t)(g * 2 + 1) * 512 + r] = make_float4(v[4], v[5], v[6], v[7]);
    }
}

// ---------------------------------------------------------------------------
// Pre-kernel 2: csq[k] = ||c_k||^2 fp32; pads 500..511 with +INF.
// ---------------------------------------------------------------------------
__global__ void csq_kernel(const float* __restrict__ c, float* __restrict__ csq) {
    int wid  = (blockIdx.x * blockDim.x + threadIdx.x) >> 6;
    int lane = threadIdx.x & 63;
    if (wid >= KPAD) return;
    if (wid >= K_C) { if (lane == 0) csq[wid] = INFINITY; return; }
    const float* row = c + (size_t)wid * DIM;
    float s = 0.f;
    #pragma unroll
    for (int j = 0; j < DIM / 64; ++j) {
        float v = row[lane + j * 64];
        s += v * v;
    }
    #pragma unroll
    for (int m = 32; m; m >>= 1) s += __shfl_xor(s, m, 64);
    if (lane == 0) csq[wid] = s;
}

// ---------------------------------------------------------------------------
// Main kernel (unchanged from round 16 — at the 2-block-residency staging
// ceiling ~10.7 B/cyc/CU): BM=64, BK=64, 12 slots, 512 thr, acc 64,
// 4 waves/SIMD, 2 blocks/CU, LDS 76.8 KB.
// ---------------------------------------------------------------------------
__global__ __launch_bounds__(THREADS, 4) void kmeans_mfma(
        const float* __restrict__ x, const char* __restrict__ ws,
        int* __restrict__ out) {
    __shared__ __align__(16) ushort Bh[8][KPAD][8];      // 64 KB
    __shared__ __align__(16) ushort Ah[8][BM][8];        // 8 KB
    __shared__ float rv1[4][BM];                         // 1 KB
    __shared__ float rv2[4][BM];                         // 1 KB
    __shared__ int   ridx[4][BM];                        // 1 KB

    const int tid  = threadIdx.x;
    const int w    = tid >> 6;          // wave 0..7
    const int lane = tid & 63;
    const int l31  = lane & 31;
    const int lh   = lane >> 5;
    const int wm   = w >> 2;            // 0..1 row half (32 rows each)
    const int wn   = w & 3;             // 0..3 col quarter (128 cols each)
    const int rowBase = blockIdx.x * BM;

    // A staging (ALL 512 threads): thread t -> row t>>3 (0..63), chunk j = t&7
    const int srow = tid >> 3;
    const int sj   = tid & 7;
    const int sslot = srow ^ (sj << 1);   // bank-spread write slot
    const float* xsrc = x + (size_t)(rowBase + srow) * DIM + sj * 8;

    const char* wsChi = ws + WS_CHI;
    const float* csq  = (const float*)(ws + WS_CSQ);
    int* count = (int*)ws;
    int* list  = (int*)(ws + WS_LIST);

    f32x16 acc[4] = {};

    // ---- preload + convert A tile 0 ----
    uint4 hv;
    {
        float4 xa = *reinterpret_cast<const float4*>(xsrc);
        float4 xb = *reinterpret_cast<const float4*>(xsrc + 4);
        float v[8] = {xa.x, xa.y, xa.z, xa.w, xb.x, xb.y, xb.z, xb.w};
        uint h[8];
        #pragma unroll
        for (int e = 0; e < 8; ++e) h[e] = f2bf(v[e]);
        hv = make_uint4(h[0] | (h[1] << 16), h[2] | (h[3] << 16),
                        h[4] | (h[5] << 16), h[6] | (h[7] << 16));
    }

    for (int kt = 0; kt < NKT; ++kt) {
        __syncthreads();   // (a) prev compute done; Bh/Ah safe to overwrite

        // ---- stage B(kt): 8 waves x 8 KB = 64 KB via global_load_lds ----
        {
            const char* sH = wsChi + (size_t)kt * 65536 + w * 8192 + lane * 16;
            char* dH = ((char*)Bh) + w * 8192;
            #pragma unroll
            for (int i = 0; i < 8; ++i) GLOAD16(sH + i * 1024, dH + i * 1024);
        }
        // ---- A write (pre-converted regs -> LDS, swizzled slot) ----
        *reinterpret_cast<uint4*>(&Ah[sj][sslot][0]) = hv;

        __syncthreads();   // (b) compiler drains vmcnt+lgkm: staged data visible

        // ---- prefetch next A floats (hidden under compute) ----
        float4 xa, xb;
        if (kt + 1 < NKT) {
            xa = *reinterpret_cast<const float4*>(xsrc + (kt + 1) * BK);
            xb = *reinterpret_cast<const float4*>(xsrc + (kt + 1) * BK + 4);
        }

        // ---- compute: 4 k-steps of 16, 4 MFMAs each ----
        __builtin_amdgcn_s_setprio(1);
        #pragma unroll
        for (int ks = 0; ks < 4; ++ks) {
            const int j = ks * 2 + lh;                     // chunk 0..7
            const int rsl = (wm * 32 + l31) ^ (j << 1);    // read slot (swizzle inverse)
            bf16x8 ah0 = *(const bf16x8*)&Ah[j][rsl][0];

            const ushort* pBh = &Bh[j][wn * 128 + l31][0];
            #pragma unroll
            for (int nf = 0; nf < 4; ++nf) {
                bf16x8 bh = *(const bf16x8*)(pBh + nf * 32 * 8);
                acc[nf] = __builtin_amdgcn_mfma_f32_32x32x16_bf16(ah0, bh, acc[nf], 0, 0, 0);
            }
        }
        __builtin_amdgcn_s_setprio(0);

        // ---- convert next A tile ----
        if (kt + 1 < NKT) {
            float v[8] = {xa.x, xa.y, xa.z, xa.w, xb.x, xb.y, xb.z, xb.w};
            uint h[8];
            #pragma unroll
            for (int e = 0; e < 8; ++e) h[e] = f2bf(v[e]);
            hv = make_uint4(h[0] | (h[1] << 16), h[2] | (h[3] << 16),
                            h[4] | (h[5] << 16), h[6] | (h[7] << 16));
        }
    }

    // ---- epilogue: per-row (best, second, idx) over this wave's 128 cols ----
    float cq[4];
    #pragma unroll
    for (int nf = 0; nf < 4; ++nf) cq[nf] = csq[wn * 128 + nf * 32 + l31];

    #pragma unroll
    for (int reg = 0; reg < 16; ++reg) {
        float v[4]; int col[4];
        #pragma unroll
        for (int nf = 0; nf < 4; ++nf) {
            v[nf]   = fmaf(-2.f, acc[nf][reg], cq[nf]);
            col[nf] = wn * 128 + nf * 32 + l31;
        }
        float paL, paH; int paI;
        if (v[1] < v[0]) { paL = v[1]; paI = col[1]; paH = v[0]; }
        else             { paL = v[0]; paI = col[0]; paH = v[1]; }
        float pbL, pbH; int pbI;
        if (v[3] < v[2]) { pbL = v[3]; pbI = col[3]; pbH = v[2]; }
        else             { pbL = v[2]; pbI = col[2]; pbH = v[3]; }
        float b1, b2; int i1;
        if (pbL < paL) { b1 = pbL; i1 = pbI; b2 = fminf(paL, pbH); }
        else           { b1 = paL; i1 = paI; b2 = fminf(pbL, paH); }
        #pragma unroll
        for (int m = 1; m < 32; m <<= 1) {
            float o1 = __shfl_xor(b1, m, 64);
            float o2 = __shfl_xor(b2, m, 64);
            int   oi = __shfl_xor(i1, m, 64);
            b2 = fminf(fminf(b2, o2), fmaxf(b1, o1));
            if (o1 < b1 || (o1 == b1 && oi < i1)) { b1 = o1; i1 = oi; }
        }
        int row = wm * 32 + (reg & 3) + 8 * (reg >> 2) + 4 * lh;
        if (l31 == 0) { rv1[wn][row] = b1; rv2[wn][row] = b2; ridx[wn][row] = i1; }
    }
    __syncthreads();

    // ---- merge 4 col-quarters per row, write out, flag tight margins ----
    if (tid < BM) {
        float b1 = INFINITY, b2 = INFINITY; int i1 = 0;
        #pragma unroll
        for (int ww = 0; ww < 4; ++ww) {
            float a1 = rv1[ww][tid], a2 = rv2[ww][tid];
            int   ai = ridx[ww][tid];
            b2 = fminf(fminf(b2, a2), fmaxf(b1, a1));
            if (a1 < b1 || (a1 == b1 && ai < i1)) { b1 = a1; i1 = ai; }
        }
        out[rowBase + tid] = i1;
        if (b2 - b1 < TAU) {
            int p = atomicAdd(count, 1);
            list[p] = rowBase + tid;
        }
    }
}

// ---------------------------------------------------------------------------
// Rescue v5: exact fp32, register-tiled, COALESCED center loads.
// If use_ct: centers read from the fp32 transposed layout ct4[dq*512 + k]
// (lanes read consecutive k -> 1 line/wave instead of 64). Else: v4 fallback
// (row-major streams). 512 threads = 2 row-groups x 256 center-pairs;
// per thread 8 rows x 2 centers; xs reads are wave-uniform LDS broadcasts.
// ---------------------------------------------------------------------------
#define FMA_BLOCK                                                             \
    {                                                                         \
        _Pragma("unroll")                                                     \
        for (int i = 0; i < 8; ++i) {                                         \
            float4 xv = *reinterpret_cast<const float4*>(&xs[rg * 8 + i][dq * 4]); \
            d0[i] = fmaf(xv.x, cv0.x, d0[i]);                                 \
            d0[i] = fmaf(xv.y, cv0.y, d0[i]);                                 \
            d0[i] = fmaf(xv.z, cv0.z, d0[i]);                                 \
            d0[i] = fmaf(xv.w, cv0.w, d0[i]);                                 \
            d1[i] = fmaf(xv.x, cv1.x, d1[i]);                                 \
            d1[i] = fmaf(xv.y, cv1.y, d1[i]);                                 \
            d1[i] = fmaf(xv.z, cv1.z, d1[i]);                                 \
            d1[i] = fmaf(xv.w, cv1.w, d1[i]);                                 \
        }                                                                     \
    }

__global__ __launch_bounds__(512) void rescue_kernel(
        const float* __restrict__ x, const float* __restrict__ c,
        const char* __restrict__ ws, int use_ct, int* __restrict__ out) {
    __shared__ __align__(16) float xs[16][DIM];   // 48 KB
    __shared__ float mv[16][4];
    __shared__ int   mi[16][4];
    __shared__ int   rows_s[16];
    const float* csq = (const float*)(ws + WS_CSQ);
    const int* list  = (const int*)(ws + WS_LIST);
    const float4* ct4 = (const float4*)(ws + WS_CT);
    const int n = *(const int*)ws;
    const int tid  = threadIdx.x;
    const int wv   = tid >> 6;          // wave 0..7
    const int rg   = tid >> 8;          // row group 0..1 (rows rg*8..+7)
    const int cg   = tid & 255;         // center pair id
    const int k0 = cg;                  // centers k0, k0+256 (asc for ties)
    const int k1 = cg + 256;
    const float* c0 = c + (size_t)min(k0, K_C - 1) * DIM;
    const float* c1 = c + (size_t)min(k1, K_C - 1) * DIM;
    const float cq0 = csq[k0];
    const float cq1 = csq[k1];

    for (int g = blockIdx.x; g * 16 < n; g += gridDim.x) {
        const int base = g * 16;
        const int cnt  = min(16, n - base);
        if (tid < 16) rows_s[tid] = list[base + min(tid, cnt - 1)];
        __syncthreads();
        for (int idx = tid; idx < 16 * (DIM / 4); idx += 512) {
            int r = idx / (DIM / 4), dc = idx - r * (DIM / 4);
            *reinterpret_cast<float4*>(&xs[r][dc * 4]) =
                *reinterpret_cast<const float4*>(&x[(size_t)rows_s[r] * DIM + dc * 4]);
        }
        __syncthreads();

        float d0[8], d1[8];
        #pragma unroll
        for (int i = 0; i < 8; ++i) { d0[i] = 0.f; d1[i] = 0.f; }

        if (use_ct) {
            #pragma unroll 2
            for (int dq = 0; dq < DIM / 4; ++dq) {
                float4 cv0 = ct4[(size_t)dq * 512 + cg];
                float4 cv1 = ct4[(size_t)dq * 512 + cg + 256];
                FMA_BLOCK
            }
        } else {
            #pragma unroll 2
            for (int dq = 0; dq < DIM / 4; ++dq) {
                float4 cv0 = *reinterpret_cast<const float4*>(&c0[dq * 4]);
                float4 cv1 = *reinterpret_cast<const float4*>(&c1[dq * 4]);
                FMA_BLOCK
            }
        }

        float bv[8]; int bi[8];
        #pragma unroll
        for (int i = 0; i < 8; ++i) {
            float v0 = fmaf(-2.f, d0[i], cq0);
            float v1 = fmaf(-2.f, d1[i], cq1);
            if (v1 < v0) { bv[i] = v1; bi[i] = k1; }
            else         { bv[i] = v0; bi[i] = k0; }   // k0 < k1: ties keep k0
        }
        #pragma unroll
        for (int m = 1; m < 64; m <<= 1) {
            #pragma unroll
            for (int i = 0; i < 8; ++i) {
                float ov = __shfl_xor(bv[i], m, 64);
                int   oi = __shfl_xor(bi[i], m, 64);
                if (ov < bv[i] || (ov == bv[i] && oi < bi[i])) { bv[i] = ov; bi[i] = oi; }
            }
        }
        if ((tid & 63) == 0) {
            #pragma unroll
            for (int i = 0; i < 8; ++i) { mv[rg * 8 + i][wv & 3] = bv[i]; mi[rg * 8 + i][wv & 3] = bi[i]; }
        }
        __syncthreads();
        if (tid < cnt) {
            float b = mv[tid][0]; int i = mi[tid][0];
            #pragma unroll
            for (int q = 1; q < 4; ++q) {
                if (mv[tid][q] < b || (mv[tid][q] == b && mi[tid][q] < i)) {
                    b = mv[tid][q]; i = mi[tid][q];
                }
            }
            out[rows_s[tid]] = i;
        }
        __syncthreads();
    }
}

extern "C" void kernel_launch(void* const* d_in, const int* in_sizes, int n_in,
                              void* d_out, int out_size, void* d_ws, size_t ws_size,
                              hipStream_t stream) {
    const float* x = (const float*)d_in[0];
    const float* c = (const float*)d_in[1];
    char* ws = (char*)d_ws;
    int* out = (int*)d_out;
    const int use_ct = (ws_size >= (size_t)WS_NEED) ? 1 : 0;

    convert_kernel<<<dim3(192), dim3(256), 0, stream>>>(
        c, (ushort*)(ws + WS_CHI), (float4*)(ws + WS_CT), use_ct, (int*)ws);
    csq_kernel<<<dim3(128), dim3(256), 0, stream>>>(c, (float*)(ws + WS_CSQ));
    kmeans_mfma<<<dim3(NROWS / BM), dim3(THREADS), 0, stream>>>(x, ws, out);
    rescue_kernel<<<dim3(256), dim3(512), 0, stream>>>(x, c, ws, use_ct, out);
}